// Round 7
// baseline (397.324 us; speedup 1.0000x reference)
//
#include <hip/hip_runtime.h>

#define Tn 64
#define Bn 16384
#define Vn 29
#define Hn 20

typedef float f4 __attribute__((ext_vector_type(4)));
typedef float f2 __attribute__((ext_vector_type(2)));

static __device__ __forceinline__ f4 ld4u(const float* p) {
  f4 v; __builtin_memcpy(&v, p, 16); return v;
}
static __device__ __forceinline__ f2 ld2u(const float* p) {
  f2 v; __builtin_memcpy(&v, p, 8); return v;
}
static __device__ __forceinline__ void st4u(float* p, f4 v) {
  __builtin_memcpy(p, &v, 16);
}

#define LOG2E 1.4426950408889634f
#define LN2   0.6931471805599453f

static __device__ __forceinline__ float frcp(float x) {
#if __has_builtin(__builtin_amdgcn_rcpf)
  return __builtin_amdgcn_rcpf(x);
#else
  return 1.0f / x;
#endif
}
static __device__ __forceinline__ float fexp2(float x) {
#if __has_builtin(__builtin_amdgcn_exp2f)
  return __builtin_amdgcn_exp2f(x);
#else
  return exp2f(x);
#endif
}
static __device__ __forceinline__ float flog2(float x) {
#if __has_builtin(__builtin_amdgcn_logf)
  return __builtin_amdgcn_logf(x);
#else
  return log2f(x);
#endif
}
static __device__ __forceinline__ float ftanh(float x) {
  float e = fexp2(x * (2.0f * LOG2E));
  return 1.0f - 2.0f * frcp(1.0f + e);
}

// ds_swizzle BitMode: src = ((lane & and) | or) ^ xor, within 32-lane halves
#define SWZ(v, imm) __int_as_float(__builtin_amdgcn_ds_swizzle(__float_as_int(v), (imm)))
#define P16(ow) (((ow) << 5) | 0x10)   /* broadcast from lane ow of each 16-group */
#define P8(ow)  (((ow) << 5) | 0x18)   /* broadcast from lane ow of each 8-group  */

#if __has_builtin(__builtin_amdgcn_update_dpp)
#define DPPF(v, ctrl) __int_as_float(__builtin_amdgcn_update_dpp( \
    0, __float_as_int(v), (ctrl), 0xF, 0xF, true))
#define DPP_XOR1(v) DPPF(v, 0xB1)   /* quad_perm [1,0,3,2] */
#define DPP_XOR2(v) DPPF(v, 0x4E)   /* quad_perm [2,3,0,1] */
#else
#define DPP_XOR1(v) SWZ(v, 0x041F)
#define DPP_XOR2(v) SWZ(v, 0x081F)
#endif

// ============================ Phase A: recurrence ============================
// 16 lanes / batch element. Lane j owns hidden rows rA=j and rB=j+16 (j<4,
// clamped otherwise; clamped lanes' rB results are never stored/broadcast).
// x cols owned pairwise: lane j<14 -> cols 2j,2j+1; lane14 -> col 28.

// xi accumulate, c = literal vocab col: owner lane c>>1, slot c&1
#define XIA_STEP(c) { \
  float xb_ = SWZ(((c) & 1) ? xN1.y : xN1.x, P16((c) >> 1)); \
  aA += wiA[(c)] * xb_; aB += wiB[(c)] * xb_; }
#define XIA_ALL \
  XIA_STEP(0)  XIA_STEP(1)  XIA_STEP(2)  XIA_STEP(3)  XIA_STEP(4)  \
  XIA_STEP(5)  XIA_STEP(6)  XIA_STEP(7)  XIA_STEP(8)  XIA_STEP(9)  \
  XIA_STEP(10) XIA_STEP(11) XIA_STEP(12) XIA_STEP(13) XIA_STEP(14) \
  XIA_STEP(15) XIA_STEP(16) XIA_STEP(17) XIA_STEP(18) XIA_STEP(19) \
  XIA_STEP(20) XIA_STEP(21) XIA_STEP(22) XIA_STEP(23) XIA_STEP(24) \
  XIA_STEP(25) XIA_STEP(26) XIA_STEP(27) XIA_STEP(28)

// same ladder but sourcing from xv (prologue, t=0)
#define XI0_STEP(c) { \
  float xb_ = SWZ(((c) & 1) ? xv.y : xv.x, P16((c) >> 1)); \
  aA += wiA[(c)] * xb_; aB += wiB[(c)] * xb_; }
#define XI0_ALL \
  XI0_STEP(0)  XI0_STEP(1)  XI0_STEP(2)  XI0_STEP(3)  XI0_STEP(4)  \
  XI0_STEP(5)  XI0_STEP(6)  XI0_STEP(7)  XI0_STEP(8)  XI0_STEP(9)  \
  XI0_STEP(10) XI0_STEP(11) XI0_STEP(12) XI0_STEP(13) XI0_STEP(14) \
  XI0_STEP(15) XI0_STEP(16) XI0_STEP(17) XI0_STEP(18) XI0_STEP(19) \
  XI0_STEP(20) XI0_STEP(21) XI0_STEP(22) XI0_STEP(23) XI0_STEP(24) \
  XI0_STEP(25) XI0_STEP(26) XI0_STEP(27) XI0_STEP(28)

// recurrent term, k = literal hidden idx: h_k owned by lane k (k<16) slot A,
// else lane k-16 slot B. Broadcast and consume inline (no hbc array).
#define WH_STEP(k) { \
  float hk_ = SWZ(((k) < 16) ? hA : hB, P16(((k) < 16) ? (k) : ((k) - 16))); \
  aA += hk_ * whA[(k)]; aB += hk_ * whB[(k)]; }
#define WH_ALL \
  WH_STEP(0)  WH_STEP(1)  WH_STEP(2)  WH_STEP(3)  WH_STEP(4)  \
  WH_STEP(5)  WH_STEP(6)  WH_STEP(7)  WH_STEP(8)  WH_STEP(9)  \
  WH_STEP(10) WH_STEP(11) WH_STEP(12) WH_STEP(13) WH_STEP(14) \
  WH_STEP(15) WH_STEP(16) WH_STEP(17) WH_STEP(18) WH_STEP(19)

// lane j<14: cols 2j,2j+1 ; j==14: col 28 ; j==15: unused
static __device__ __forceinline__ f2 ldx16(const float* row, int j) {
  f2 v;
  if (j < 14)      v = ld2u(row + 2 * j);
  else if (j == 14) v = f2{row[28], 0.0f};
  else              v = f2{0.0f, 0.0f};
  return v;
}

__global__ __launch_bounds__(256) void k_rec(
    const float* __restrict__ x,  const float* __restrict__ img,
    const float* __restrict__ Wi, const float* __restrict__ bi,
    const float* __restrict__ Wh, const float* __restrict__ bh,
    float* __restrict__ hs)
{
  const int gt = blockIdx.x * 256 + threadIdx.x;
  const int b = gt >> 4;
  const int j = gt & 15;

  const int rA = j;                          // 0..15
  const int rB = (j < 4) ? (j + 16) : 19;    // 16..19 (clamped dup elsewhere)

  // Wi rows (29 floats, unaligned)
  float wiA[Vn], wiB[Vn];
#pragma unroll
  for (int q = 0; q < 7; ++q) {
    f4 a = ld4u(Wi + rA * Vn + 4 * q);
    f4 c = ld4u(Wi + rB * Vn + 4 * q);
    wiA[4*q]=a.x; wiA[4*q+1]=a.y; wiA[4*q+2]=a.z; wiA[4*q+3]=a.w;
    wiB[4*q]=c.x; wiB[4*q+1]=c.y; wiB[4*q+2]=c.z; wiB[4*q+3]=c.w;
  }
  wiA[28] = Wi[rA * Vn + 28];
  wiB[28] = Wi[rB * Vn + 28];

  // Wh rows (20 floats, 16B-aligned 80B rows)
  float whA[Hn], whB[Hn];
#pragma unroll
  for (int q = 0; q < 5; ++q) {
    f4 a = *(const f4*)(Wh + rA * Hn + 4 * q);
    f4 c = *(const f4*)(Wh + rB * Hn + 4 * q);
    whA[4*q]=a.x; whA[4*q+1]=a.y; whA[4*q+2]=a.z; whA[4*q+3]=a.w;
    whB[4*q]=c.x; whB[4*q+1]=c.y; whB[4*q+2]=c.z; whB[4*q+3]=c.w;
  }

  const float bsA = bi[rA] + bh[rA];
  const float bsB = bi[rB] + bh[rB];

  const size_t S = (size_t)Bn * Vn;
  const float* xrow = x + (size_t)b * Vn;

  f2 xv  = ldx16(xrow, j);            // x(0)
  f2 xN1 = ldx16(xrow + S, j);        // x(1)
  f2 xN2 = ldx16(xrow + 2 * S, j);    // x(2)
  const float* pf = xrow + 3 * S;

  // xi(0) = x(0)@Wi^T + bias + img
  float aA = bsA + img[(size_t)b * Hn + rA];
  float aB = bsB + img[(size_t)b * Hn + rB];
  XI0_ALL

  float hA = 0.0f, hB = 0.0f;         // h_{-1} = 0 (WH ladder adds 0 at t=0)

  float* hp = hs + (size_t)b * Hn;    // [t][b][20], t-stride Bn*Hn
  const size_t hstep = (size_t)Bn * Hn;

#pragma unroll 1
  for (int t = 0; t < Tn; ++t) {
    f2 xC = ldx16(pf, j);             // x(t+3), clamped
    if (t < 60) pf += S;

    // aA/aB currently hold xi(t); add recurrent term via inline broadcast
    WH_ALL
    hA = ftanh(aA);
    hB = ftanh(aB);

    hp[rA] = hA;
    if (j < 4) hp[16 + j] = hB;
    hp += hstep;

    // xi(t+1) for next iteration (t=63's result is discarded; xN1 clamped dup)
    aA = bsA; aB = bsB;
    XIA_ALL
    xN1 = xN2; xN2 = xC;
  }
  (void)xv;
}

// ====================== Phase B: logits + log-softmax ========================
// 8 lanes / element, grid-strided 8 elems per group. Lane j owns vocab rows
// 4j..4j+3 (clamped, bias-masked) and loads h[3j..3j+2] (clamped).

#define OWN(k) ((k) >= 18 ? 6 : (k) / 3)
#define HSEL(k) (((k) - 3 * OWN(k)) == 0 ? hl0 : (((k) - 3 * OWN(k)) == 1 ? hl1 : hl2))
#define LG_STEP(k) { \
  float hk_ = SWZ(HSEL(k), P8(OWN(k))); \
  l0 += hk_ * wo0[(k)]; l1 += hk_ * wo1[(k)]; \
  l2 += hk_ * wo2[(k)]; l3 += hk_ * wo3[(k)]; }
#define LG_ALL \
  LG_STEP(0)  LG_STEP(1)  LG_STEP(2)  LG_STEP(3)  LG_STEP(4)  \
  LG_STEP(5)  LG_STEP(6)  LG_STEP(7)  LG_STEP(8)  LG_STEP(9)  \
  LG_STEP(10) LG_STEP(11) LG_STEP(12) LG_STEP(13) LG_STEP(14) \
  LG_STEP(15) LG_STEP(16) LG_STEP(17) LG_STEP(18) LG_STEP(19)

#define OUT_ITERS 8

__global__ __launch_bounds__(256) void k_out(
    const float* __restrict__ hs, const float* __restrict__ Who,
    const float* __restrict__ bho, float* __restrict__ out)
{
  const int gt = blockIdx.x * 256 + threadIdx.x;
  const int g = gt >> 3;            // group id, 0..131071
  const int j = gt & 7;
  const int NG = (gridDim.x * 256) >> 3;   // 131072 groups

  float wo0[Hn], wo1[Hn], wo2[Hn], wo3[Hn];
  float bo0, bo1, bo2, bo3;
  {
    int v0 = 4 * j, v1 = 4 * j + 1, v2 = 4 * j + 2, v3 = 4 * j + 3;
    int c0v = v0 > 28 ? 28 : v0, c1v = v1 > 28 ? 28 : v1;
    int c2v = v2 > 28 ? 28 : v2, c3v = v3 > 28 ? 28 : v3;
#pragma unroll
    for (int q = 0; q < 5; ++q) {
      f4 w0 = *(const f4*)(Who + c0v * Hn + 4 * q);
      f4 w1 = *(const f4*)(Who + c1v * Hn + 4 * q);
      f4 w2 = *(const f4*)(Who + c2v * Hn + 4 * q);
      f4 w3 = *(const f4*)(Who + c3v * Hn + 4 * q);
      wo0[4*q]=w0.x; wo0[4*q+1]=w0.y; wo0[4*q+2]=w0.z; wo0[4*q+3]=w0.w;
      wo1[4*q]=w1.x; wo1[4*q+1]=w1.y; wo1[4*q+2]=w1.z; wo1[4*q+3]=w1.w;
      wo2[4*q]=w2.x; wo2[4*q+1]=w2.y; wo2[4*q+2]=w2.z; wo2[4*q+3]=w2.w;
      wo3[4*q]=w3.x; wo3[4*q+1]=w3.y; wo3[4*q+2]=w3.z; wo3[4*q+3]=w3.w;
    }
    bo0 = (v0 < Vn) ? bho[v0] : -1e30f;
    bo1 = (v1 < Vn) ? bho[v1] : -1e30f;
    bo2 = (v2 < Vn) ? bho[v2] : -1e30f;
    bo3 = (v3 < Vn) ? bho[v3] : -1e30f;
  }

  int c0 = 3 * j;     c0 = c0 > 19 ? 19 : c0;
  int c1 = 3 * j + 1; c1 = c1 > 19 ? 19 : c1;
  int c2 = 3 * j + 2; c2 = c2 > 19 ? 19 : c2;

  size_t e = (size_t)g;
  const float* hp = hs + e * Hn;
  float hl0 = hp[c0], hl1 = hp[c1], hl2 = hp[c2];

#pragma unroll 1
  for (int it = 0; it < OUT_ITERS; ++it) {
    // prefetch next element's h (double-buffered)
    float nl0 = 0.0f, nl1 = 0.0f, nl2 = 0.0f;
    if (it + 1 < OUT_ITERS) {
      const float* np = hs + (e + NG) * Hn;
      nl0 = np[c0]; nl1 = np[c1]; nl2 = np[c2];
    }

    float l0 = bo0, l1 = bo1, l2 = bo2, l3 = bo3;
    LG_ALL

    float m = fmaxf(fmaxf(l0, l1), fmaxf(l2, l3));
    m = fmaxf(m, DPP_XOR1(m));
    m = fmaxf(m, DPP_XOR2(m));
    m = fmaxf(m, SWZ(m, 0x101F));
    float e0 = fexp2((l0 - m) * LOG2E), e1 = fexp2((l1 - m) * LOG2E);
    float e2 = fexp2((l2 - m) * LOG2E), e3 = fexp2((l3 - m) * LOG2E);
    float s = e0 + e1 + e2 + e3;
    s += DPP_XOR1(s);
    s += DPP_XOR2(s);
    s += SWZ(s, 0x101F);
    float ls = m + flog2(s) * LN2;

    float* op = out + e * Vn + 4 * j;
    f4 o = f4{l0 - ls, l1 - ls, l2 - ls, l3 - ls};
    if (j < 7) st4u(op, o);
    else       op[0] = l0 - ls;

    hl0 = nl0; hl1 = nl1; hl2 = nl2;
    e += NG;
  }
}

extern "C" void kernel_launch(void* const* d_in, const int* in_sizes, int n_in,
                              void* d_out, int out_size, void* d_ws, size_t ws_size,
                              hipStream_t stream)
{
  const float* x   = (const float*)d_in[0];
  const float* img = (const float*)d_in[1];
  const float* Wi  = (const float*)d_in[2];
  const float* bi  = (const float*)d_in[3];
  const float* Wh  = (const float*)d_in[4];
  const float* bh  = (const float*)d_in[5];
  const float* Who = (const float*)d_in[6];
  const float* bho = (const float*)d_in[7];
  float* out = (float*)d_out;
  float* hws = (float*)d_ws;    // [T][B][20] = 83.9 MB

  // Phase A: recurrence, 16 lanes/elem -> 16*B threads
  k_rec<<<(16 * Bn) / 256, 256, 0, stream>>>(x, img, Wi, bi, Wh, bh, hws);
  // Phase B: logits+softmax, 8 lanes/elem, 8 elems/group -> T*B*8/8 threads
  k_out<<<(Tn * Bn * 8 / OUT_ITERS) / 256, 256, 0, stream>>>(hws, Who, bho, out);
}

// Round 8
// 335.192 us; speedup vs baseline: 1.1854x; 1.1854x over previous
//
#include <hip/hip_runtime.h>

#define Tn 64
#define Bn 16384
#define Vn 29
#define Hn 20

typedef float f4 __attribute__((ext_vector_type(4)));

static __device__ __forceinline__ f4 ld4u(const float* p) {
  f4 v; __builtin_memcpy(&v, p, 16); return v;
}
static __device__ __forceinline__ void st4u(float* p, f4 v) {
  __builtin_memcpy(p, &v, 16);
}

#define LOG2E 1.4426950408889634f
#define LN2   0.6931471805599453f

static __device__ __forceinline__ float frcp(float x) {
#if __has_builtin(__builtin_amdgcn_rcpf)
  return __builtin_amdgcn_rcpf(x);
#else
  return 1.0f / x;
#endif
}
static __device__ __forceinline__ float fexp2(float x) {
#if __has_builtin(__builtin_amdgcn_exp2f)
  return __builtin_amdgcn_exp2f(x);
#else
  return exp2f(x);
#endif
}
static __device__ __forceinline__ float flog2(float x) {
#if __has_builtin(__builtin_amdgcn_logf)
  return __builtin_amdgcn_logf(x);
#else
  return log2f(x);
#endif
}
static __device__ __forceinline__ float ftanh(float x) {
  float e = fexp2(x * (2.0f * LOG2E));
  return 1.0f - 2.0f * frcp(1.0f + e);
}

// DPP: broadcast lane j (0..3) of each quad to all 4 quad lanes. Pure VALU.
#define DPPF(v, ctrl) __int_as_float(__builtin_amdgcn_update_dpp( \
    0, __float_as_int(v), (ctrl), 0xF, 0xF, true))
#define DPPB(v, j) DPPF(v, ((j) == 0 ? 0x00 : ((j) == 1 ? 0x55 : ((j) == 2 ? 0xAA : 0xFF))))

// ===========================================================================
// K1: xi[t][b][h] = x[t,b,:]@Wi[h,:] + bi[h] + bh[h] + (t==0)*img[b,h]
// Thread per (t,b). Weights are wave-uniform -> SGPR broadcast (s_load +
// v_fmac with SGPR operand). No LDS, no swizzle. Memory-bound by design.
// ===========================================================================
__global__ __launch_bounds__(256) void k_pre(
    const float* __restrict__ x, const float* __restrict__ img,
    const float* __restrict__ Wi, const float* __restrict__ bi,
    const float* __restrict__ bh, float* __restrict__ xi)
{
  const int e = blockIdx.x * 256 + threadIdx.x;   // 0 .. T*B-1
  const int t = e >> 14;                          // B = 16384
  const int b = e & (Bn - 1);

  const float* xr = x + (size_t)e * Vn;
  float xv[Vn];
#pragma unroll
  for (int q = 0; q < 7; ++q) {
    f4 v = ld4u(xr + 4 * q);
    xv[4*q] = v.x; xv[4*q+1] = v.y; xv[4*q+2] = v.z; xv[4*q+3] = v.w;
  }
  xv[28] = xr[28];

  const bool first = (t == 0);
  const float* ia = img + (size_t)b * Hn;
  float* orow = xi + (size_t)e * Hn;              // 80B rows, 16B-aligned

#pragma unroll
  for (int hb = 0; hb < 5; ++hb) {
    float acc[4];
#pragma unroll
    for (int r = 0; r < 4; ++r) {
      const int h = hb * 4 + r;
      float a = bi[h] + bh[h];                    // uniform -> SGPR
#pragma unroll
      for (int k = 0; k < Vn; ++k)
        a += Wi[h * Vn + k] * xv[k];              // uniform weight -> SGPR
      acc[r] = a;
    }
    if (first) {
      f4 iv = *(const f4*)(ia + hb * 4);          // img rows 80B -> aligned
      acc[0] += iv.x; acc[1] += iv.y; acc[2] += iv.z; acc[3] += iv.w;
    }
    st4u(orow + hb * 4, f4{acc[0], acc[1], acc[2], acc[3]});
  }
}

// ===========================================================================
// K2: recurrence h_t = tanh(xi_t + Wh h_{t-1}), h written IN PLACE over xi.
// 4 lanes per batch element; lane j owns hidden rows 5j..5j+4 (Wh: 100 VGPR).
// h-broadcast via DPP quad_perm (VALU) -> zero LDS-pipe traffic.
// ===========================================================================
#define HSEL4(k) ((k) % 5 == 0 ? hr0 : ((k) % 5 == 1 ? hr1 : \
                  ((k) % 5 == 2 ? hr2 : ((k) % 5 == 3 ? hr3 : hr4))))
#define WH4_STEP(k) { float hk_ = DPPB(HSEL4(k), (k) / 5); \
  a0 += hk_ * wh0[(k)]; a1 += hk_ * wh1[(k)]; a2 += hk_ * wh2[(k)]; \
  a3 += hk_ * wh3[(k)]; a4 += hk_ * wh4[(k)]; }
#define WH4_ALL \
  WH4_STEP(0)  WH4_STEP(1)  WH4_STEP(2)  WH4_STEP(3)  WH4_STEP(4)  \
  WH4_STEP(5)  WH4_STEP(6)  WH4_STEP(7)  WH4_STEP(8)  WH4_STEP(9)  \
  WH4_STEP(10) WH4_STEP(11) WH4_STEP(12) WH4_STEP(13) WH4_STEP(14) \
  WH4_STEP(15) WH4_STEP(16) WH4_STEP(17) WH4_STEP(18) WH4_STEP(19)

__global__ __launch_bounds__(256) void k_rec(
    float* __restrict__ ws, const float* __restrict__ Wh)
{
  const int gt = blockIdx.x * 256 + threadIdx.x;  // 4*B threads
  const int b = gt >> 2;
  const int j = gt & 3;

  // Wh rows 5j..5j+4 (80B rows -> f4-aligned)
  float wh0[Hn], wh1[Hn], wh2[Hn], wh3[Hn], wh4[Hn];
#pragma unroll
  for (int q = 0; q < 5; ++q) {
    f4 v0 = *(const f4*)(Wh + (5*j+0) * Hn + 4*q);
    f4 v1 = *(const f4*)(Wh + (5*j+1) * Hn + 4*q);
    f4 v2 = *(const f4*)(Wh + (5*j+2) * Hn + 4*q);
    f4 v3 = *(const f4*)(Wh + (5*j+3) * Hn + 4*q);
    f4 v4 = *(const f4*)(Wh + (5*j+4) * Hn + 4*q);
    wh0[4*q]=v0.x; wh0[4*q+1]=v0.y; wh0[4*q+2]=v0.z; wh0[4*q+3]=v0.w;
    wh1[4*q]=v1.x; wh1[4*q+1]=v1.y; wh1[4*q+2]=v1.z; wh1[4*q+3]=v1.w;
    wh2[4*q]=v2.x; wh2[4*q+1]=v2.y; wh2[4*q+2]=v2.z; wh2[4*q+3]=v2.w;
    wh3[4*q]=v3.x; wh3[4*q+1]=v3.y; wh3[4*q+2]=v3.z; wh3[4*q+3]=v3.w;
    wh4[4*q]=v4.x; wh4[4*q+1]=v4.y; wh4[4*q+2]=v4.z; wh4[4*q+3]=v4.w;
  }

  float* p = ws + (size_t)b * Hn + 5 * j;         // lane's 5-float slot
  const size_t step = (size_t)Bn * Hn;

  // prefetch xi(0..2); 5 floats = unaligned f4 + scalar
  f4 c4 = ld4u(p);              float c1 = p[4];
  f4 n4 = ld4u(p + step);       float n1 = p[4 + step];
  f4 m4 = ld4u(p + 2 * step);   float m1 = p[4 + 2 * step];
  const float* pf = p + 3 * step;

  float hr0 = 0.f, hr1 = 0.f, hr2 = 0.f, hr3 = 0.f, hr4 = 0.f;

#pragma unroll 1
  for (int t = 0; t < Tn; ++t) {
    f4 q4 = c4; float q1 = 0.f;                   // dummy init
    if (t < Tn - 3) { q4 = ld4u(pf); q1 = pf[4]; pf += step; }

    float a0 = c4.x, a1 = c4.y, a2 = c4.z, a3 = c4.w, a4 = c1;
    WH4_ALL
    hr0 = ftanh(a0); hr1 = ftanh(a1); hr2 = ftanh(a2);
    hr3 = ftanh(a3); hr4 = ftanh(a4);

    st4u(p, f4{hr0, hr1, hr2, hr3});              // overwrite xi[t] with h[t]
    p[4] = hr4;
    p += step;

    c4 = n4; c1 = n1; n4 = m4; n1 = m1; m4 = q4; m1 = q1;
  }
}

// ===========================================================================
// K3: logits + log-softmax. Thread per (t,b); Who wave-uniform -> SGPR;
// fully serial per-thread softmax (no cross-lane ops). Memory-bound.
// ===========================================================================
__global__ __launch_bounds__(256) void k_out(
    const float* __restrict__ hs, const float* __restrict__ Who,
    const float* __restrict__ bho, float* __restrict__ out)
{
  const size_t e = (size_t)blockIdx.x * 256 + threadIdx.x;  // 0 .. T*B-1

  const float* hp = hs + e * Hn;                  // 80B rows, aligned
  float hv[Hn];
#pragma unroll
  for (int q = 0; q < 5; ++q) {
    f4 v = *(const f4*)(hp + 4 * q);
    hv[4*q] = v.x; hv[4*q+1] = v.y; hv[4*q+2] = v.z; hv[4*q+3] = v.w;
  }

  float lg[Vn];
#pragma unroll
  for (int v = 0; v < Vn; ++v) {
    float a = bho[v];                             // uniform -> SGPR
#pragma unroll
    for (int k = 0; k < Hn; ++k)
      a += Who[v * Hn + k] * hv[k];               // uniform -> SGPR
    lg[v] = a;
  }

  float m = lg[0];
#pragma unroll
  for (int v = 1; v < Vn; ++v) m = fmaxf(m, lg[v]);
  float s = 0.f;
#pragma unroll
  for (int v = 0; v < Vn; ++v) s += fexp2((lg[v] - m) * LOG2E);
  const float ls = m + flog2(s) * LN2;

  float* op = out + e * Vn;
#pragma unroll
  for (int q = 0; q < 7; ++q)
    st4u(op + 4 * q, f4{lg[4*q] - ls, lg[4*q+1] - ls, lg[4*q+2] - ls, lg[4*q+3] - ls});
  op[28] = lg[28] - ls;
}

extern "C" void kernel_launch(void* const* d_in, const int* in_sizes, int n_in,
                              void* d_out, int out_size, void* d_ws, size_t ws_size,
                              hipStream_t stream)
{
  const float* x   = (const float*)d_in[0];
  const float* img = (const float*)d_in[1];
  const float* Wi  = (const float*)d_in[2];
  const float* bi  = (const float*)d_in[3];
  const float* Wh  = (const float*)d_in[4];
  const float* bh  = (const float*)d_in[5];
  const float* Who = (const float*)d_in[6];
  const float* bho = (const float*)d_in[7];
  float* out = (float*)d_out;
  float* ws  = (float*)d_ws;    // [T][B][20] = 83.9 MB; xi then h in place

  // K1: xi precompute, thread per (t,b)
  k_pre<<<(Tn * Bn) / 256, 256, 0, stream>>>(x, img, Wi, bi, bh, ws);
  // K2: recurrence, 4 lanes per batch element, h overwrites xi in ws
  k_rec<<<(4 * Bn) / 256, 256, 0, stream>>>(ws, Wh);
  // K3: logits + log-softmax, thread per (t,b)
  k_out<<<(Tn * Bn) / 256, 256, 0, stream>>>(ws, Who, bho, out);
}